// Round 10
// baseline (71.664 us; speedup 1.0000x reference)
//
#include <hip/hip_runtime.h>
#include <stdint.h>

#define NB 16
#define NC 256
#define NH 48
#define NW 64
#define ND 21
#define HW (NH * NW)
#define ROW_ELEMS (NW * NC)   // one (b,y) row: 16384 bf16 = 32KB
#define NXCD 8
#define NWG (NB * NH)         // 768 (convert grid)
#define PL_LD 35              // private plane leading dim (scatter ~2-way)
#define PLANE (ND * PL_LD)    // 735 floats
#define WSTR  (2 * PLANE)     // per-wave double-buffered region (1470 floats)

typedef __bf16 bf16x8 __attribute__((ext_vector_type(8)));
typedef float f32x4 __attribute__((ext_vector_type(4)));

// convert grid (768): XCD k owns wg [k*96, k*96+96) = batches {2k,2k+1}
__device__ __forceinline__ int xcd_wg(int orig) {
    return (orig & (NXCD - 1)) * (NWG / NXCD) + (orig >> 3);
}

// full-row LDS layout [pos][c] bf16, XOR-swizzled 16B chunks (conflict-free b128)
__device__ __forceinline__ int sw_addr(int x, int chunk) {
    int cs = (chunk & ~7) | ((chunk ^ x) & 7);
    return x * 256 + (cs << 3);
}
// parity permutation: even x -> pos 0..31, odd x -> pos 32..63
__device__ __forceinline__ int posx(int x) { return ((x & 1) << 5) | (x >> 1); }

// ws (in2) GLOBAL fragment order: slice w=(nt<<1)|par, per-kb 1KB contiguous
__device__ __forceinline__ int frag_off(int w, int kb, int l) {
    return w * 4096 + kb * 512 + ((l ^ ((w & 3) << 1)) << 3);
}

__device__ __forceinline__ bf16x8 load_pack8(const float* __restrict__ p, int cbase) {
    bf16x8 v;
#pragma unroll
    for (int j = 0; j < 8; ++j)
        v[j] = (__bf16)p[(size_t)(cbase + j) * HW];
    return v;
}

// ---------- pre-pass: in2 fp32 [b][c][h][w] -> ws bf16 rows (fragment order) --
__global__ void __launch_bounds__(256, 4)
convert_in2(const float* __restrict__ in2, unsigned short* __restrict__ ws) {
    __shared__ unsigned short s[ROW_ELEMS];
    const int tid = threadIdx.x;
    const int wg = xcd_wg(blockIdx.x);
    const int b = wg / NH, y = wg % NH;
    const int x = tid & 63, g0 = tid >> 6;
    const int par = x & 1, m_lo = (x >> 1) & 15, nt = x >> 5;
    const int w = (nt << 1) | par;
    const float* p = in2 + ((size_t)b * NC * NH + y) * NW + x;
#pragma unroll
    for (int i = 0; i < 8; ++i) {
        const int chunk = g0 * 8 + i;
        const int kb = chunk >> 2, quad = chunk & 3;
        const int l = (quad << 4) | m_lo;
        bf16x8 v = load_pack8(p, chunk * 8);
        *(bf16x8*)&s[frag_off(w, kb, l)] = v;
    }
    __syncthreads();
    unsigned short* wr = ws + ((size_t)b * NH + y) * ROW_ELEMS;
#pragma unroll
    for (int i = 0; i < 8; ++i) {
        const int e = (i * 256 + tid) * 8;
        *(bf16x8*)(wr + e) = *(const bf16x8*)(s + e);
    }
}

// ---------- main: block = (b, P, 6-y group, ys-half); 256 blocks x 768 ------
// BARRIER-FREE main loop: B read per-wave direct from L2-resident ws (no
// shared staging buffer), epilogue transpose in per-wave-private LDS planes.
// Waves self-schedule; the R2-R9 lockstep convoy (the conserved ~130k cy/CU)
// is structurally removed.
__global__ void __launch_bounds__(768, 1)
corr_main(const float* __restrict__ in1, const unsigned short* __restrict__ ws,
          float* __restrict__ out) {
    // loop: 12 private regions of 2x[ND][PL_LD] floats (70560 B total)
    // prologue overlay: two 32KB in1-row staging regions
    __shared__ __align__(16) unsigned char smem[70656];
    unsigned short* reg0 = (unsigned short*)smem;
    unsigned short* reg1 = (unsigned short*)(smem + 32768);

    const int tid = threadIdx.x;
    const int bid = blockIdx.x;
    const int xcd = bid & 7;                   // all blocks of b on one XCD
    const int u   = bid >> 3;                  // 0..31
    const int b   = 2 * xcd + (u >> 4);
    const int v   = u & 15;
    const int P   = v & 1, g = (v >> 1) & 3, half = v >> 3;
    const int y0  = 12 * g + P;
    const int lane = tid & 63, wave = tid >> 6;   // 12 waves
    const int m_lo = lane & 15, quad = lane >> 4;
    const int par  = wave & 1, yy = wave >> 1;    // wave = (par, yy)
    const int y    = y0 + 2 * yy;                 // this wave's output row

    const int lo = max(y0 - 20, P);
    const int hi = min(y0 + 30, 46 + P);
    const int n  = ((hi - lo) >> 1) + 1;          // 16..22
    const int n0 = (n + 1) >> 1;
    const int lo_h = half ? (lo + 2 * n0) : lo;
    const int nh   = half ? (n - n0) : n0;        // >= 8 always

    // ---- prologue: stage 6 in1 rows (2 per round), wave (yy>>1)==rnd extracts
    bf16x8 afrag[2][8];
#pragma unroll 1
    for (int rnd = 0; rnd < 3; ++rnd) {
        const int yA = y0 + 4 * rnd;              // rows yA, yA+2
#pragma unroll
        for (int i = 0; i < 6; ++i) {
            const int uu = i * 768 + tid;
            if (uu < 4096) {
                const int row = uu >> 11, cu = uu & 2047;
                const int x = cu & 63, chunk = cu >> 6;
                const float* p = in1 + ((size_t)b * NC * NH + (yA + 2 * row)) * NW + x;
                bf16x8 vv = load_pack8(p, chunk * 8);
                unsigned short* dst = row ? reg1 : reg0;
                *(bf16x8*)&dst[sw_addr(posx(x), chunk)] = vv;
            }
        }
        __syncthreads();
        if ((yy >> 1) == rnd) {
            const unsigned short* src = (yy & 1) ? reg1 : reg0;
            const int pos0 = par * 32 + m_lo;
#pragma unroll
            for (int kb = 0; kb < 8; ++kb) {
                afrag[0][kb] = *(const bf16x8*)&src[sw_addr(pos0,      4 * kb + quad)];
                afrag[1][kb] = *(const bf16x8*)&src[sw_addr(pos0 + 16, 4 * kb + quad)];
            }
        }
        __syncthreads();   // last one protects the overlay before sout zeroing
    }

    // private sout region; zero both bufs once (unwritten slots = out-of-band
    // outputs, stay zero; scatter footprint is step-invariant)
    float* mysout = (float*)smem + wave * WSTR;
    for (int i = lane; i < WSTR; i += 64) mysout[i] = 0.0f;

    // zero this half's out-of-range dy planes (per par-pair, full columns)
    float* outyy = out + (size_t)b * (ND * ND) * HW + (size_t)y * NW;
    const int d0 = (y >= 20) ? 0 : ((21 - y) >> 1);
    const int d1 = min(20, (67 - y) >> 1);
    const int zlo = half ? (d1 + 1) : 0;
    const int zhi = half ? ND : d0;
    const int t2  = par * 64 + lane;              // 0..127 in wave-pair
    for (int z = zlo; z < zhi; ++z) {
        float* ob = outyy + (size_t)z * ND * HW;
#pragma unroll
        for (int i = 0; i < 11; ++i) {
            const int e = i * 128 + t2;
            if (e < ND * NW)
                __builtin_nontemporal_store(0.0f, &ob[(size_t)(e >> 6) * HW + (e & 63)]);
        }
    }

    const float scale = 1.0f / 256.0f;
    const unsigned short* wsb = ws + (size_t)b * NH * ROW_ELEMS;
    const int boff0 = frag_off((0 << 1) | par, 0, lane);
    const int boff1 = frag_off((1 << 1) | par, 0, lane);

    // this wave's valid k-range: dyi(k) = D0 + k in [0,20]
    const int D0 = ((lo_h - y) >> 1) + 10;
    const int ka = max(0, -D0);
    const int kb_ = min(nh - 1, 20 - D0);

    // drain a private plane buf to global (own parity columns, stride 2;
    // complementary wave fills the other half of each line concurrently)
    auto drain = [&](int bufi, int dyp) {
        const float* sp = mysout + bufi * PLANE;
        float* ob = outyy + (size_t)dyp * ND * HW;
#pragma unroll
        for (int i = 0; i < 11; ++i) {
            const int e = i * 64 + lane;
            if (e < ND * 32)
                __builtin_nontemporal_store(sp[(e >> 5) * PL_LD + (e & 31)] * scale,
                                            &ob[(size_t)(e >> 5) * HW + 2 * (e & 31) + par]);
        }
    };

    // BARRIER-FREE per-wave loop. Per step: issue slice0 loads -> drain prev
    // plane (covers load latency) -> MFMA pair0 -> slice1 loads (reuse regs)
    // -> MFMA pair1 -> scatter into private buf. All waits are per-wave
    // compiler-counted vmcnt/lgkmcnt; waves desynchronize freely.
    for (int k = ka; k <= kb_; ++k) {
        const int ys = lo_h + 2 * k;
        const unsigned short* row = wsb + (size_t)ys * ROW_ELEMS;

        bf16x8 B[8];
#pragma unroll
        for (int kb = 0; kb < 8; ++kb)
            B[kb] = *(const bf16x8*)&row[boff0 + kb * 512];

        if (k > ka) drain((k & 1) ^ 1, D0 + k - 1);

        f32x4 a00 = {0,0,0,0}, a10 = {0,0,0,0};
#pragma unroll
        for (int kb = 0; kb < 8; ++kb) {
            a00 = __builtin_amdgcn_mfma_f32_16x16x32_bf16(afrag[0][kb], B[kb], a00, 0, 0, 0);
            a10 = __builtin_amdgcn_mfma_f32_16x16x32_bf16(afrag[1][kb], B[kb], a10, 0, 0, 0);
        }
#pragma unroll
        for (int kb = 0; kb < 8; ++kb)
            B[kb] = *(const bf16x8*)&row[boff1 + kb * 512];
        f32x4 a01 = {0,0,0,0}, a11 = {0,0,0,0};
#pragma unroll
        for (int kb = 0; kb < 8; ++kb) {
            a01 = __builtin_amdgcn_mfma_f32_16x16x32_bf16(afrag[0][kb], B[kb], a01, 0, 0, 0);
            a11 = __builtin_amdgcn_mfma_f32_16x16x32_bf16(afrag[1][kb], B[kb], a11, 0, 0, 0);
        }

        float* sp = mysout + (k & 1) * PLANE;
#pragma unroll
        for (int mm = 0; mm < 2; ++mm)
#pragma unroll
        for (int nn = 0; nn < 2; ++nn)
#pragma unroll
        for (int r = 0; r < 4; ++r) {
            const int xh  = 16 * mm + 4 * quad + r;
            const int dxi = 16 * nn + m_lo - xh + 10;
            const float vv = mm == 0 ? (nn == 0 ? a00[r] : a01[r])
                                     : (nn == 0 ? a10[r] : a11[r]);
            if ((unsigned)dxi <= 20u) sp[dxi * PL_LD + xh] = vv;
        }
    }
    // epilogue: drain the final step's plane (per-wave, no sync needed)
    if (ka <= kb_) drain(kb_ & 1, D0 + kb_);
}

// ---------- fallback (round-1 style) if ws is too small ----------------------
__global__ void __launch_bounds__(256, 2)
corr_fallback(const float* __restrict__ in1, const float* __restrict__ in2,
              float* __restrict__ out) {
    __shared__ unsigned short s1[ROW_ELEMS];
    __shared__ unsigned short s2[ROW_ELEMS];
    const int tid = threadIdx.x;
    const int b = blockIdx.x / NH, y = blockIdx.x % NH;
    const int lane = tid & 63, wave = tid >> 6;
    const int m_lo = lane & 15, quad = lane >> 4;
    const int asub = wave >> 1, bsub = wave & 1;
    {
        const int x = tid & 63, g0 = tid >> 6;
        const float* p = in1 + ((size_t)b * NC * NH + y) * NW + x;
        for (int i = 0; i < 8; ++i) {
            const int chunk = g0 * 8 + i;
            bf16x8 v = load_pack8(p, chunk * 8);
            *(bf16x8*)&s1[sw_addr(x, chunk)] = v;
        }
    }
    __syncthreads();
    bf16x8 afrag[2][8];
    for (int mm = 0; mm < 2; ++mm) {
        const int x = 32 * asub + 16 * mm + m_lo;
        for (int kb = 0; kb < 8; ++kb)
            afrag[mm][kb] = *(const bf16x8*)&s1[sw_addr(x, 4 * kb + quad)];
    }
    const float scale = 1.0f / 256.0f;
    for (int dyi = 0; dyi < ND; ++dyi) {
        const int ys = y + 2 * dyi - 20;
        float* ob = out + (((size_t)b * (ND * ND) + (size_t)dyi * ND) * NH + y) * NW;
        if ((unsigned)ys >= (unsigned)NH) {
            for (int i = tid; i < ND * NW; i += 256)
                ob[(size_t)(i >> 6) * HW + (i & 63)] = 0.0f;
            continue;
        }
        __syncthreads();
        {
            const int x = tid & 63, g0 = tid >> 6;
            const float* p = in2 + ((size_t)b * NC * NH + ys) * NW + x;
            for (int i = 0; i < 8; ++i) {
                const int chunk = g0 * 8 + i;
                bf16x8 v = load_pack8(p, chunk * 8);
                *(bf16x8*)&s2[sw_addr(x, chunk)] = v;
            }
        }
        __syncthreads();
        f32x4 acc[2][2];
        for (int mm = 0; mm < 2; ++mm)
            for (int nn = 0; nn < 2; ++nn) acc[mm][nn] = (f32x4){0.f, 0.f, 0.f, 0.f};
        for (int nn = 0; nn < 2; ++nn) {
            const int xpp = 32 * bsub + 16 * nn + m_lo;
            for (int kb = 0; kb < 8; ++kb) {
                bf16x8 bfrag = *(const bf16x8*)&s2[sw_addr(xpp, 4 * kb + quad)];
                acc[0][nn] = __builtin_amdgcn_mfma_f32_16x16x32_bf16(afrag[0][kb], bfrag, acc[0][nn], 0, 0, 0);
                acc[1][nn] = __builtin_amdgcn_mfma_f32_16x16x32_bf16(afrag[1][kb], bfrag, acc[1][nn], 0, 0, 0);
            }
        }
        for (int mm = 0; mm < 2; ++mm)
            for (int nn = 0; nn < 2; ++nn) {
                const int xb = 32 * asub + 16 * mm + 4 * quad;
                const int xpp = 32 * bsub + 16 * nn + m_lo;
                for (int r = 0; r < 4; ++r) {
                    const int x = xb + r, d = xpp - x;
                    if (d >= -20 && d <= 20 && !(d & 1))
                        ob[(size_t)((d + 20) >> 1) * HW + x] = acc[mm][nn][r] * scale;
                }
            }
        for (int i = tid; i < ND * 20; i += 256) {
            const int dxi = i / 20, j = i - dxi * 20;
            const int dx = 2 * dxi - 20, a = dx < 0 ? -dx : dx;
            if (j < a) {
                const int x = dx < 0 ? j : (NW - dx + j);
                ob[(size_t)dxi * HW + x] = 0.0f;
            }
        }
    }
}

extern "C" void kernel_launch(void* const* d_in, const int* in_sizes, int n_in,
                              void* d_out, int out_size, void* d_ws, size_t ws_size,
                              hipStream_t stream) {
    const float* in1 = (const float*)d_in[0];
    const float* in2 = (const float*)d_in[1];
    float* out = (float*)d_out;
    const size_t need = (size_t)NB * NH * ROW_ELEMS * sizeof(unsigned short);
    if (ws_size >= need) {
        convert_in2<<<dim3(NWG), dim3(256), 0, stream>>>(in2, (unsigned short*)d_ws);
        corr_main<<<dim3(256), dim3(768), 0, stream>>>(in1, (const unsigned short*)d_ws, out);
    } else {
        corr_fallback<<<dim3(NWG), dim3(256), 0, stream>>>(in1, in2, out);
    }
}

// Round 11
// 67.992 us; speedup vs baseline: 1.0540x; 1.0540x over previous
//
#include <hip/hip_runtime.h>
#include <stdint.h>

#define NB 16
#define NC 256
#define NH 48
#define NW 64
#define ND 21
#define HW (NH * NW)
#define ROW_ELEMS (NW * NC)   // one (b,y) row: 16384 bf16 = 32KB
#define NXCD 8
#define NWG (NB * NH)         // 768 (convert grid)
#define SO_LD 65              // padded plane leading dim (scatter <=4-way)
#define SO_SZ (ND * SO_LD)    // 1365 floats per plane

typedef __bf16 bf16x8 __attribute__((ext_vector_type(8)));
typedef float f32x4 __attribute__((ext_vector_type(4)));

// direct global->LDS DMA, 16B per lane; LDS dest = uniform base + lane*16
#define GLOAD_LDS16(g, l) __builtin_amdgcn_global_load_lds(               \
    (const __attribute__((address_space(1))) unsigned int*)(g),           \
    (__attribute__((address_space(3))) unsigned int*)(l), 16, 0, 0)

// convert grid (768): XCD k owns wg [k*96, k*96+96) = batches {2k,2k+1}
__device__ __forceinline__ int xcd_wg(int orig) {
    return (orig & (NXCD - 1)) * (NWG / NXCD) + (orig >> 3);
}

// full-row LDS layout [pos][c] bf16, XOR-swizzled 16B chunks (conflict-free b128)
__device__ __forceinline__ int sw_addr(int x, int chunk) {
    int cs = (chunk & ~7) | ((chunk ^ x) & 7);
    return x * 256 + (cs << 3);
}
// parity permutation: even x -> pos 0..31, odd x -> pos 32..63
__device__ __forceinline__ int posx(int x) { return ((x & 1) << 5) | (x >> 1); }

// ws (in2) GLOBAL fragment order: slice w=(nt<<1)|par, per-kb 1KB contiguous
__device__ __forceinline__ int frag_off(int w, int kb, int l) {
    return w * 4096 + kb * 512 + ((l ^ ((w & 3) << 1)) << 3);
}

__device__ __forceinline__ bf16x8 load_pack8(const float* __restrict__ p, int cbase) {
    bf16x8 v;
#pragma unroll
    for (int j = 0; j < 8; ++j)
        v[j] = (__bf16)p[(size_t)(cbase + j) * HW];
    return v;
}

// ---------- pre-pass: in2 fp32 [b][c][h][w] -> ws bf16 rows (fragment order) --
__global__ void __launch_bounds__(256, 4)
convert_in2(const float* __restrict__ in2, unsigned short* __restrict__ ws) {
    __shared__ unsigned short s[ROW_ELEMS];
    const int tid = threadIdx.x;
    const int wg = xcd_wg(blockIdx.x);
    const int b = wg / NH, y = wg % NH;
    const int x = tid & 63, g0 = tid >> 6;
    const int par = x & 1, m_lo = (x >> 1) & 15, nt = x >> 5;
    const int w = (nt << 1) | par;
    const float* p = in2 + ((size_t)b * NC * NH + y) * NW + x;
#pragma unroll
    for (int i = 0; i < 8; ++i) {
        const int chunk = g0 * 8 + i;
        const int kb = chunk >> 2, quad = chunk & 3;
        const int l = (quad << 4) | m_lo;
        bf16x8 v = load_pack8(p, chunk * 8);
        *(bf16x8*)&s[frag_off(w, kb, l)] = v;
    }
    __syncthreads();
    unsigned short* wr = ws + ((size_t)b * NH + y) * ROW_ELEMS;
#pragma unroll
    for (int i = 0; i < 8; ++i) {
        const int e = (i * 256 + tid) * 8;
        *(bf16x8*)(wr + e) = *(const bf16x8*)(s + e);
    }
}

// ---------- main: block = (b, P, 3-y group, ys-half); 512 blocks x 384 ------
// Half-size blocks -> 2 INDEPENDENT blocks per CU: whole-block stalls
// (barriers, staging bursts, prologue) overlap with the co-resident block.
// Proven R7/R9 step pieces kept: gload_lds staging, counted vmcnt, full-line
// wave-pair drains, fragment ws layout, padded sout scatter.
__global__ void __launch_bounds__(384, 3)
corr_main(const float* __restrict__ in1, const unsigned short* __restrict__ ws,
          float* __restrict__ out) {
    // [0,32768): bbuf (single-buffered B row; also prologue in1 staging)
    // [32768,65528): 6 sout planes [ND][SO_LD] (two sets of 3)
    __shared__ __align__(16) unsigned char smem[65536];
    unsigned short* bbuf  = (unsigned short*)smem;
    float*          soutf = (float*)(smem + 32768);

    const int tid = threadIdx.x;
    const int bid = blockIdx.x;
    const int xcd = bid & 7;                   // all blocks of b on one XCD
    const int r   = bid >> 3;                  // 0..63
    const int b   = 2 * xcd + (r >> 5);
    const int v   = r & 31;
    const int P   = v & 1, g = (v >> 1) & 7, half = (v >> 4) & 1;
    const int y0  = 6 * g + P;
    const int lane = tid & 63, wave = tid >> 6;   // 6 waves
    const int m_lo = lane & 15, quad = lane >> 4;
    const int par  = wave & 1, yy = wave >> 1;    // wave = (par, yy in 0..2)
    const int y    = y0 + 2 * yy;                 // this wave's output row

    const int lo = max(y0 - 20, P);
    const int hi = min(y0 + 24, 46 + P);
    const int n  = ((hi - lo) >> 1) + 1;          // 13..22
    const int n0 = (n + 1) >> 1;
    const int lo_h = half ? (lo + 2 * n0) : lo;
    const int nh   = half ? (n - n0) : n0;        // >= 6 always

    const unsigned short* wsb = ws + (size_t)b * NH * ROW_ELEMS;

    // ---- prologue: 3 rounds; stage in1 row y0+2*rnd into bbuf; wave-pair
    // yy==rnd extracts its A fragments
    bf16x8 afrag[2][8];
#pragma unroll 1
    for (int rnd = 0; rnd < 3; ++rnd) {
        const int yr = y0 + 2 * rnd;
        const float* pr = in1 + ((size_t)b * NC * NH + yr) * NW;
#pragma unroll
        for (int i = 0; i < 6; ++i) {
            const int pk = i * 384 + tid;          // 2048 packs per row
            if (pk < 2048) {
                const int x = pk & 63, ch = pk >> 6;
                bf16x8 vv = load_pack8(pr + x, ch * 8);
                *(bf16x8*)&bbuf[sw_addr(posx(x), ch)] = vv;
            }
        }
        __syncthreads();
        if (yy == rnd) {
            const int pos0 = par * 32 + m_lo;
#pragma unroll
            for (int kb = 0; kb < 8; ++kb) {
                afrag[0][kb] = *(const bf16x8*)&bbuf[sw_addr(pos0,      4 * kb + quad)];
                afrag[1][kb] = *(const bf16x8*)&bbuf[sw_addr(pos0 + 16, 4 * kb + quad)];
            }
        }
        __syncthreads();
    }

    // ---- first B row DMA into bbuf (waves 0-3: 6 chunks, waves 4-5: 4)
    const int gl0 = (wave < 4) ? wave * 6 : 24 + (wave - 4) * 4;
    {
        const unsigned short* row = wsb + (size_t)lo_h * ROW_ELEMS;
        asm volatile("" ::: "memory");
        if (wave < 4) {
#pragma unroll
            for (int i = 0; i < 6; ++i)
                GLOAD_LDS16(row + (gl0 + i) * 512 + lane * 8, bbuf + (gl0 + i) * 512);
        } else {
#pragma unroll
            for (int i = 0; i < 4; ++i)
                GLOAD_LDS16(row + (gl0 + i) * 512 + lane * 8, bbuf + (gl0 + i) * 512);
        }
        asm volatile("" ::: "memory");
    }

    // zero both sout plane sets (band-invalid slots stay zero forever)
    for (int i = tid; i < 6 * SO_SZ; i += 384) soutf[i] = 0.0f;

    // zero this wave-pair's out-of-range dy planes (full-line nt stores)
    float* outyy = out + (size_t)b * (ND * ND) * HW + (size_t)y * NW;
    const int d0 = (y >= 20) ? 0 : ((21 - y) >> 1);
    const int d1 = min(20, (67 - y) >> 1);
    const int zlo = half ? (d1 + 1) : 0;
    const int zhi = half ? ND : d0;
    const int t2  = par * 64 + lane;              // 0..127 in wave-pair
    for (int z = zlo; z < zhi; ++z) {
        float* ob = outyy + (size_t)z * ND * HW;
#pragma unroll
        for (int i = 0; i < 11; ++i) {
            const int e = i * 128 + t2;
            if (e < ND * NW)
                __builtin_nontemporal_store(0.0f, &ob[(size_t)(e >> 6) * HW + (e & 63)]);
        }
    }
    // publish first B row (one-time full drain is fine here)
    asm volatile("s_waitcnt vmcnt(0) lgkmcnt(0)\n\ts_barrier" ::: "memory");

    const float scale = 1.0f / 256.0f;
    const int boff0 = frag_off((0 << 1) | par, 0, lane);
    const int boff1 = frag_off((1 << 1) | par, 0, lane);
    const int D0 = ((lo_h - y) >> 1) + 10;        // dyi at k=0

    // step: phase A [MFMA from bbuf + scatter -> set k&1] bar
    //       phase B [DMA row k+1 -> bbuf | drain prev plane <- set (k&1)^1]
    //               counted vmcnt (11 drain stores stay in flight) bar
    for (int k = 0; k < nh; ++k) {
        const int dyi = D0 + k;
        const bool valid = (unsigned)dyi <= 20u;   // wave-uniform

        if (valid) {
            f32x4 a00 = {0,0,0,0}, a01 = {0,0,0,0}, a10 = {0,0,0,0}, a11 = {0,0,0,0};
#pragma unroll
            for (int kb = 0; kb < 8; ++kb) {
                bf16x8 b0 = *(const bf16x8*)&bbuf[boff0 + kb * 512];
                bf16x8 b1 = *(const bf16x8*)&bbuf[boff1 + kb * 512];
                a00 = __builtin_amdgcn_mfma_f32_16x16x32_bf16(afrag[0][kb], b0, a00, 0, 0, 0);
                a10 = __builtin_amdgcn_mfma_f32_16x16x32_bf16(afrag[1][kb], b0, a10, 0, 0, 0);
                a01 = __builtin_amdgcn_mfma_f32_16x16x32_bf16(afrag[0][kb], b1, a01, 0, 0, 0);
                a11 = __builtin_amdgcn_mfma_f32_16x16x32_bf16(afrag[1][kb], b1, a11, 0, 0, 0);
            }
            float* sp = soutf + ((k & 1) * 3 + yy) * SO_SZ;
#pragma unroll
            for (int mm = 0; mm < 2; ++mm)
#pragma unroll
            for (int nn = 0; nn < 2; ++nn)
#pragma unroll
            for (int r2 = 0; r2 < 4; ++r2) {
                const int xh  = 16 * mm + 4 * quad + r2;
                const int dxi = (16 * nn + m_lo) - xh + 10;
                const float vv = mm == 0 ? (nn == 0 ? a00[r2] : a01[r2])
                                         : (nn == 0 ? a10[r2] : a11[r2]);
                if ((unsigned)dxi <= 20u)
                    sp[dxi * SO_LD + 2 * xh + par] = vv;
            }
        }
        asm volatile("s_waitcnt lgkmcnt(0)\n\ts_barrier" ::: "memory");

        // phase B
        const bool more = (k + 1 < nh);
        if (more) {
            const unsigned short* row = wsb + (size_t)(lo_h + 2 * (k + 1)) * ROW_ELEMS;
            asm volatile("" ::: "memory");
            if (wave < 4) {
#pragma unroll
                for (int i = 0; i < 6; ++i)
                    GLOAD_LDS16(row + (gl0 + i) * 512 + lane * 8, bbuf + (gl0 + i) * 512);
            } else {
#pragma unroll
                for (int i = 0; i < 4; ++i)
                    GLOAD_LDS16(row + (gl0 + i) * 512 + lane * 8, bbuf + (gl0 + i) * 512);
            }
            asm volatile("" ::: "memory");
        }
        const int dyp = dyi - 1;
        const bool drain = (k > 0) && ((unsigned)dyp <= 20u);
        if (drain) {
            const float* sp = soutf + (((k & 1) ^ 1) * 3 + yy) * SO_SZ;
            float* ob = outyy + (size_t)dyp * ND * HW;
#pragma unroll
            for (int i = 0; i < 11; ++i) {
                const int e = i * 128 + t2;
                if (e < ND * NW)
                    __builtin_nontemporal_store(sp[(e >> 6) * SO_LD + (e & 63)] * scale,
                                                &ob[(size_t)(e >> 6) * HW + (e & 63)]);
            }
        }
        if (more) {
            if (drain)
                asm volatile("s_waitcnt lgkmcnt(0) vmcnt(11)\n\ts_barrier" ::: "memory");
            else
                asm volatile("s_waitcnt lgkmcnt(0) vmcnt(0)\n\ts_barrier" ::: "memory");
        } else {
            asm volatile("s_waitcnt lgkmcnt(0)\n\ts_barrier" ::: "memory");
        }
    }

    // epilogue: drain the final step's plane (visibility via last barrier)
    {
        const int dyL = D0 + nh - 1;
        if ((unsigned)dyL <= 20u) {
            const float* sp = soutf + (((nh - 1) & 1) * 3 + yy) * SO_SZ;
            float* ob = outyy + (size_t)dyL * ND * HW;
#pragma unroll
            for (int i = 0; i < 11; ++i) {
                const int e = i * 128 + t2;
                if (e < ND * NW)
                    __builtin_nontemporal_store(sp[(e >> 6) * SO_LD + (e & 63)] * scale,
                                                &ob[(size_t)(e >> 6) * HW + (e & 63)]);
            }
        }
    }
}

// ---------- fallback (round-1 style) if ws is too small ----------------------
__global__ void __launch_bounds__(256, 2)
corr_fallback(const float* __restrict__ in1, const float* __restrict__ in2,
              float* __restrict__ out) {
    __shared__ unsigned short s1[ROW_ELEMS];
    __shared__ unsigned short s2[ROW_ELEMS];
    const int tid = threadIdx.x;
    const int b = blockIdx.x / NH, y = blockIdx.x % NH;
    const int lane = tid & 63, wave = tid >> 6;
    const int m_lo = lane & 15, quad = lane >> 4;
    const int asub = wave >> 1, bsub = wave & 1;
    {
        const int x = tid & 63, g0 = tid >> 6;
        const float* p = in1 + ((size_t)b * NC * NH + y) * NW + x;
        for (int i = 0; i < 8; ++i) {
            const int chunk = g0 * 8 + i;
            bf16x8 v = load_pack8(p, chunk * 8);
            *(bf16x8*)&s1[sw_addr(x, chunk)] = v;
        }
    }
    __syncthreads();
    bf16x8 afrag[2][8];
    for (int mm = 0; mm < 2; ++mm) {
        const int x = 32 * asub + 16 * mm + m_lo;
        for (int kb = 0; kb < 8; ++kb)
            afrag[mm][kb] = *(const bf16x8*)&s1[sw_addr(x, 4 * kb + quad)];
    }
    const float scale = 1.0f / 256.0f;
    for (int dyi = 0; dyi < ND; ++dyi) {
        const int ys = y + 2 * dyi - 20;
        float* ob = out + (((size_t)b * (ND * ND) + (size_t)dyi * ND) * NH + y) * NW;
        if ((unsigned)ys >= (unsigned)NH) {
            for (int i = tid; i < ND * NW; i += 256)
                ob[(size_t)(i >> 6) * HW + (i & 63)] = 0.0f;
            continue;
        }
        __syncthreads();
        {
            const int x = tid & 63, g0 = tid >> 6;
            const float* p = in2 + ((size_t)b * NC * NH + ys) * NW + x;
            for (int i = 0; i < 8; ++i) {
                const int chunk = g0 * 8 + i;
                bf16x8 v = load_pack8(p, chunk * 8);
                *(bf16x8*)&s2[sw_addr(x, chunk)] = v;
            }
        }
        __syncthreads();
        f32x4 acc[2][2];
        for (int mm = 0; mm < 2; ++mm)
            for (int nn = 0; nn < 2; ++nn) acc[mm][nn] = (f32x4){0.f, 0.f, 0.f, 0.f};
        for (int nn = 0; nn < 2; ++nn) {
            const int xpp = 32 * bsub + 16 * nn + m_lo;
            for (int kb = 0; kb < 8; ++kb) {
                bf16x8 bfrag = *(const bf16x8*)&s2[sw_addr(xpp, 4 * kb + quad)];
                acc[0][nn] = __builtin_amdgcn_mfma_f32_16x16x32_bf16(afrag[0][kb], bfrag, acc[0][nn], 0, 0, 0);
                acc[1][nn] = __builtin_amdgcn_mfma_f32_16x16x32_bf16(afrag[1][kb], bfrag, acc[1][nn], 0, 0, 0);
            }
        }
        for (int mm = 0; mm < 2; ++mm)
            for (int nn = 0; nn < 2; ++nn) {
                const int xb = 32 * asub + 16 * mm + 4 * quad;
                const int xpp = 32 * bsub + 16 * nn + m_lo;
                for (int r = 0; r < 4; ++r) {
                    const int x = xb + r, d = xpp - x;
                    if (d >= -20 && d <= 20 && !(d & 1))
                        ob[(size_t)((d + 20) >> 1) * HW + x] = acc[mm][nn][r] * scale;
                }
            }
        for (int i = tid; i < ND * 20; i += 256) {
            const int dxi = i / 20, j = i - dxi * 20;
            const int dx = 2 * dxi - 20, a = dx < 0 ? -dx : dx;
            if (j < a) {
                const int x = dx < 0 ? j : (NW - dx + j);
                ob[(size_t)dxi * HW + x] = 0.0f;
            }
        }
    }
}

extern "C" void kernel_launch(void* const* d_in, const int* in_sizes, int n_in,
                              void* d_out, int out_size, void* d_ws, size_t ws_size,
                              hipStream_t stream) {
    const float* in1 = (const float*)d_in[0];
    const float* in2 = (const float*)d_in[1];
    float* out = (float*)d_out;
    const size_t need = (size_t)NB * NH * ROW_ELEMS * sizeof(unsigned short);
    if (ws_size >= need) {
        convert_in2<<<dim3(NWG), dim3(256), 0, stream>>>(in2, (unsigned short*)d_ws);
        corr_main<<<dim3(512), dim3(384), 0, stream>>>(in1, (const unsigned short*)d_ws, out);
    } else {
        corr_fallback<<<dim3(NWG), dim3(256), 0, stream>>>(in1, in2, out);
    }
}